// Round 6
// baseline (256.007 us; speedup 1.0000x reference)
//
#include <hip/hip_runtime.h>
#include <cstdint>
#include <cstddef>

// Problem constants (B, S, E, H, MAXLEN) = (2, 2048, 1024, 16, 2048)
constexpr int Sn = 2048;
constexpr int En = 1024;
constexpr int Bn = 2;
constexpr int Hn = 16;
constexpr int NCH = 32;            // chunks per batch (S/CHUNK)
constexpr int CHUNK = 64;
constexpr int Mtot = Bn * Sn;      // 4096
constexpr int GCH = Mtot / CHUNK;  // 64 global chunks

typedef __bf16 bf16x8 __attribute__((ext_vector_type(8)));
typedef float  f32x4  __attribute__((ext_vector_type(4)));

__device__ __forceinline__ unsigned short f2bf(float f) {
    union { float f; uint32_t u; } v; v.f = f;
    const uint32_t u = v.u;
    return (unsigned short)((u + 0x7fffu + ((u >> 16) & 1u)) >> 16);  // RNE
}
__device__ __forceinline__ float bf2f_lo(uint32_t u) {
    union { uint32_t u; float f; } v; v.u = u << 16; return v.f;
}
__device__ __forceinline__ float bf2f_hi(uint32_t u) {
    union { uint32_t u; float f; } v; v.u = u & 0xffff0000u; return v.f;
}

// ---------------------------------------------------------------------------
// Fused fp32 -> bf16 cast of x (XN), Wv (WN), Wo (WN) in one launch.
// ---------------------------------------------------------------------------
constexpr int XN = Bn * Sn * En;   // 4194304
constexpr int WN = En * En;        // 1048576

__global__ __launch_bounds__(256)
void cast3(const float* __restrict__ x, const float* __restrict__ Wv,
           const float* __restrict__ Wo, unsigned short* __restrict__ xb,
           unsigned short* __restrict__ Wvb, unsigned short* __restrict__ Wob)
{
    const int i = (blockIdx.x * 256 + threadIdx.x) * 4;
    const float* src; unsigned short* dst; int off;
    if (i < XN)           { src = x;  dst = xb;  off = i; }
    else if (i < XN + WN) { src = Wv; dst = Wvb; off = i - XN; }
    else                  { src = Wo; dst = Wob; off = i - XN - WN; }
    const float4 v = *(const float4*)(src + off);
    ushort4 o;
    o.x = f2bf(v.x); o.y = f2bf(v.y); o.z = f2bf(v.z); o.w = f2bf(v.w);
    *(ushort4*)(dst + off) = o;
}

// ---------------------------------------------------------------------------
// bf16 MFMA GEMM (NT) with register-prefetch pipeline.
// C[m,n] = sum_k A[m,k]*W[n,k] + bias[n].
// Tile 128(M) x 64(N), BK=64, 256 threads = 4 waves in 2x2, wave tile 64x32
// (4x2 grid of 16x16x32 MFMAs, 2 k-halves). Grid (N/64, M/128) = 512 blocks
// = 2 blocks/CU.
// Staging pipeline (the R6 experiment): global -> VGPR (uint4) -> ds_write.
// Loads for iteration i+1 are issued BEFORE iteration i's compute phase;
// since they target private VGPRs (no LDS side effects) they are NOT drained
// by the __syncthreads barriers and stay in flight across the MFMAs. The
// vmcnt wait falls on the NEXT iteration's ds_write (register dependency) —
// one full compute phase after issue. LDS layout identical to the
// global_load_lds version: 1024 B chunk = 16 rows x 32 k in fragment order,
// lane l -> slot l*16 B (conflict-free b128 writes and reads).
// APPLY_MASK zeroes masked rows; OUT_BF16 stores bf16; FUSE_CSUM emits
// per-64-row-chunk column sums via butterfly shuffle (unique writer).
// ---------------------------------------------------------------------------
template<bool APPLY_MASK, bool OUT_BF16, bool FUSE_CSUM>
__global__ __launch_bounds__(256)
void gemm_pipe(const unsigned short* __restrict__ A, const unsigned short* __restrict__ Bw,
               const float* __restrict__ bias, const int* __restrict__ mask,
               void* __restrict__ Cv, float* __restrict__ csum, int M, int N, int K)
{
    __shared__ __align__(16) unsigned short As[128 * 64];  // 16 KB
    __shared__ __align__(16) unsigned short Bs[64 * 64];   // 8 KB

    const int tid  = threadIdx.x;
    const int lane = tid & 63;
    const int wv   = tid >> 6;      // wave 0..3
    const int wr   = wv >> 1;       // wave row (0..1) -> M
    const int wc   = wv & 1;        // wave col (0..1) -> N
    const int bm   = blockIdx.y * 128;
    const int bn   = blockIdx.x * 64;
    const int m16  = lane & 15;
    const int kq   = lane >> 4;     // k-quarter (staging) / row-quad (C/D)

    f32x4 acc[4][2] = {};

    // Global staging sources (same mapping as the global_load_lds version).
    const int rg0 = 2 * wv, rg1 = 2 * wv + 1;
    const unsigned short* gA0 = A  + (size_t)(bm + 16 * rg0 + m16) * K + kq * 8;
    const unsigned short* gA1 = A  + (size_t)(bm + 16 * rg1 + m16) * K + kq * 8;
    const unsigned short* gB0 = Bw + (size_t)(bn + 16 * wv  + m16) * K + kq * 8;
    // Per-thread LDS staging destinations (lane-consecutive 16 B).
    uint4* lA00 = (uint4*)&As[(rg0 * 2 + 0) * 512 + lane * 8];
    uint4* lA01 = (uint4*)&As[(rg0 * 2 + 1) * 512 + lane * 8];
    uint4* lA10 = (uint4*)&As[(rg1 * 2 + 0) * 512 + lane * 8];
    uint4* lA11 = (uint4*)&As[(rg1 * 2 + 1) * 512 + lane * 8];
    uint4* lB00 = (uint4*)&Bs[(wv  * 2 + 0) * 512 + lane * 8];
    uint4* lB01 = (uint4*)&Bs[(wv  * 2 + 1) * 512 + lane * 8];

    auto load6 = [&](uint4 r[6], int k0) {
        r[0] = *(const uint4*)(gA0 + k0); r[1] = *(const uint4*)(gA0 + k0 + 32);
        r[2] = *(const uint4*)(gA1 + k0); r[3] = *(const uint4*)(gA1 + k0 + 32);
        r[4] = *(const uint4*)(gB0 + k0); r[5] = *(const uint4*)(gB0 + k0 + 32);
    };
    auto store6 = [&](const uint4 r[6]) {
        *lA00 = r[0]; *lA01 = r[1];
        *lA10 = r[2]; *lA11 = r[3];
        *lB00 = r[4]; *lB01 = r[5];
    };
    auto compute = [&]() {
        bf16x8 af[4][2], bfr[2][2];
#pragma unroll
        for (int i = 0; i < 4; ++i)
#pragma unroll
            for (int kh = 0; kh < 2; ++kh)
                af[i][kh] = *(const bf16x8*)&As[((wr * 4 + i) * 2 + kh) * 512 + lane * 8];
#pragma unroll
        for (int j = 0; j < 2; ++j)
#pragma unroll
            for (int kh = 0; kh < 2; ++kh)
                bfr[j][kh] = *(const bf16x8*)&Bs[((wc * 2 + j) * 2 + kh) * 512 + lane * 8];
#pragma unroll
        for (int kh = 0; kh < 2; ++kh)
#pragma unroll
            for (int i = 0; i < 4; ++i)
#pragma unroll
                for (int j = 0; j < 2; ++j)
                    acc[i][j] = __builtin_amdgcn_mfma_f32_16x16x32_bf16(af[i][kh], bfr[j][kh], acc[i][j], 0, 0, 0);
    };

    uint4 rA[6], rB[6];
    load6(rA, 0);
    // K=1024, BK=64 -> 16 iterations, manually 2x unrolled (two reg sets).
    for (int it = 0; it < 8; ++it) {
        const int kbase = it * 128;
        __syncthreads();            // previous compute's LDS reads done
        store6(rA);                 // waits vmcnt for rA (loaded 1 full iter ago)
        __syncthreads();            // writes visible
        load6(rB, kbase + 64);      // in flight across the MFMAs below
        compute();

        __syncthreads();
        store6(rB);
        __syncthreads();
        if (it < 7) load6(rA, kbase + 128);
        compute();
    }

    // Epilogue. C/D layout: col = lane&15, row = (lane>>4)*4 + reg.
    float colsum[2] = {0.0f, 0.0f};
#pragma unroll
    for (int i = 0; i < 4; ++i) {
        const int r0 = bm + wr * 64 + i * 16 + kq * 4;
#pragma unroll
        for (int j = 0; j < 2; ++j) {
            const int c0 = bn + wc * 32 + j * 16 + m16;
            const float bcol = bias[c0];
#pragma unroll
            for (int r = 0; r < 4; ++r) {
                const int row = r0 + r;
                float val = acc[i][j][r] + bcol;
                if (APPLY_MASK) val = (mask[row] == 0) ? 0.0f : val;
                if (FUSE_CSUM) colsum[j] += val;
                if (OUT_BF16)
                    ((unsigned short*)Cv)[(size_t)row * N + c0] = f2bf(val);
                else
                    ((float*)Cv)[(size_t)row * N + c0] = val;
            }
        }
    }

    if (FUSE_CSUM) {
        // Wave wr's 64 rows are exactly global chunk gc = 2*blockIdx.y + wr.
        const int gc = 2 * blockIdx.y + wr;
#pragma unroll
        for (int j = 0; j < 2; ++j) {
            float s = colsum[j];
            s += __shfl_xor(s, 16, 64);
            s += __shfl_xor(s, 32, 64);
            if (kq == 0)
                csum[(size_t)gc * En + bn + wc * 32 + j * 16 + m16] = s;
        }
    }
}

// ---------------------------------------------------------------------------
// combine: inline exclusive scan of csum (32 chunk sums per column) +
// within-chunk prefix + weighted combine -> opre (bf16).
// out_pre[b,i,e] = (w2*Pref[i&~1] + (i odd)*w1*vm[i-1] + w0*(T - Pref[i])) / Z
// Z = (i&~1)*w2 + (i odd)*w1 + (S-i)*w0 + 1e-8   (pre-mask normalization)
// 2 columns/thread (same head since e is even and dh=64).
// ---------------------------------------------------------------------------
__global__ __launch_bounds__(256)
void combine(const unsigned short* __restrict__ vm, const float* __restrict__ csum,
             const float* __restrict__ hier, unsigned short* __restrict__ opre)
{
    const int ep = blockIdx.x * 256 + threadIdx.x;
    const int e = ep * 2;
    const int c = blockIdx.y;
    const int b = blockIdx.z;
    const int h = e >> 6;   // dh = 64

    const float w0 = hier[((size_t)b * Hn + h) * 3 + 0];
    const float w1 = hier[((size_t)b * Hn + h) * 3 + 1] * 0.5f;
    const float w2 = hier[((size_t)b * Hn + h) * 3 + 2] * 0.25f;

    // Inline exclusive scan over this batch's 32 chunk sums (L2-hot, 256 KB).
    float run0 = 0.0f, run1 = 0.0f, T0 = 0.0f, T1 = 0.0f;
    const int g0 = b * NCH;
    for (int c2 = 0; c2 < NCH; ++c2) {
        const size_t off = (size_t)(g0 + c2) * En + e;
        const float v0 = csum[off], v1 = csum[off + 1];
        if (c2 < c) { run0 += v0; run1 += v1; }
        T0 += v0; T1 += v1;
    }

    float prev0 = 0.0f, prev1 = 0.0f;
    const size_t base = ((size_t)b * Sn + c * CHUNK) * En + e;

    for (int t = 0; t < CHUNK; ++t) {
        const int i = c * CHUNK + t;
        const uint32_t u = *(const uint32_t*)(vm + base + (size_t)t * En);
        const float cur0 = bf2f_lo(u), cur1 = bf2f_hi(u);
        float num0, num1, Z;
        if (i & 1) {
            num0 = w2 * (run0 - prev0) + w1 * prev0 + w0 * (T0 - run0);
            num1 = w2 * (run1 - prev1) + w1 * prev1 + w0 * (T1 - run1);
            Z = (float)(i - 1) * w2 + w1 + (float)(Sn - i) * w0 + 1e-8f;
        } else {
            num0 = w2 * run0 + w0 * (T0 - run0);
            num1 = w2 * run1 + w0 * (T1 - run1);
            Z = (float)i * w2 + (float)(Sn - i) * w0 + 1e-8f;
        }
        const float rz = 1.0f / Z;
        const uint32_t o = (uint32_t)f2bf(num0 * rz) | ((uint32_t)f2bf(num1 * rz) << 16);
        *(uint32_t*)(opre + base + (size_t)t * En) = o;
        run0 += cur0; run1 += cur1;
        prev0 = cur0; prev1 = cur1;
    }
}

// ---------------------------------------------------------------------------
extern "C" void kernel_launch(void* const* d_in, const int* in_sizes, int n_in,
                              void* d_out, int out_size, void* d_ws, size_t ws_size,
                              hipStream_t stream)
{
    // 0:x 1:attention_mask 2:level_indices 3:Wq 4:bq 5:Wk 6:bk 7:Wv 8:bv 9:hier 10:Wo 11:bo
    const float* x    = (const float*)d_in[0];
    const int*   mask = (const int*)d_in[1];
    const float* Wv   = (const float*)d_in[7];
    const float* bv   = (const float*)d_in[8];
    const float* hier = (const float*)d_in[9];
    const float* Wo   = (const float*)d_in[10];
    const float* bo   = (const float*)d_in[11];
    float* out = (float*)d_out;

    const int M = Mtot, N = En, K = En;

    char* ws = (char*)d_ws;
    unsigned short* xb    = (unsigned short*)ws;  ws += (size_t)M * K * 2;        // 8 MB
    unsigned short* Wvb   = (unsigned short*)ws;  ws += (size_t)N * K * 2;        // 2 MB
    unsigned short* Wob   = (unsigned short*)ws;  ws += (size_t)N * K * 2;        // 2 MB
    unsigned short* vmb   = (unsigned short*)ws;  ws += (size_t)M * N * 2;        // 8 MB
    float*          csum  = (float*)ws;           ws += (size_t)GCH * En * 4;     // 256 KB
    unsigned short* opreb = (unsigned short*)ws;  ws += (size_t)M * N * 2;        // 8 MB

    dim3 threads(256);

    // Fused casts to bf16 (x, Wv, Wo)
    cast3<<<dim3((XN + 2 * WN) / 1024), threads, 0, stream>>>(x, Wv, Wo, xb, Wvb, Wob);

    dim3 gemm_grid(N / 64, M / 128);   // (16, 32) = 512 blocks = 2/CU

    // 1) vm = mask ? (x @ Wv.T + bv) : 0 (bf16) + fused per-chunk column sums
    gemm_pipe<true, true, true><<<gemm_grid, threads, 0, stream>>>(xb, Wvb, bv, mask, vmb, csum, M, N, K);
    // 2) weighted combine (inline csum scan) -> opre (bf16)
    combine<<<dim3(En / 512, NCH, Bn), threads, 0, stream>>>(vmb, csum, hier, opreb);
    // 3) out = opre @ Wo.T + bo (fp32 out)
    gemm_pipe<false, false, false><<<gemm_grid, threads, 0, stream>>>(opreb, Wob, bo, nullptr, out, nullptr, M, N, K);
}

// Round 7
// 170.347 us; speedup vs baseline: 1.5029x; 1.5029x over previous
//
#include <hip/hip_runtime.h>
#include <cstdint>
#include <cstddef>

// Problem constants (B, S, E, H, MAXLEN) = (2, 2048, 1024, 16, 2048)
constexpr int Sn = 2048;
constexpr int En = 1024;
constexpr int Bn = 2;
constexpr int Hn = 16;
constexpr int NCH = 32;            // chunks per batch (S/CHUNK)
constexpr int CHUNK = 64;
constexpr int Mtot = Bn * Sn;      // 4096
constexpr int GCH = Mtot / CHUNK;  // 64 global chunks

typedef __bf16 bf16x8 __attribute__((ext_vector_type(8)));
typedef float  f32x4  __attribute__((ext_vector_type(4)));

__device__ __forceinline__ unsigned short f2bf(float f) {
    union { float f; uint32_t u; } v; v.f = f;
    const uint32_t u = v.u;
    return (unsigned short)((u + 0x7fffu + ((u >> 16) & 1u)) >> 16);  // RNE
}
__device__ __forceinline__ float bf2f_lo(uint32_t u) {
    union { uint32_t u; float f; } v; v.u = u << 16; return v.f;
}
__device__ __forceinline__ float bf2f_hi(uint32_t u) {
    union { uint32_t u; float f; } v; v.u = u & 0xffff0000u; return v.f;
}

// ---------------------------------------------------------------------------
// Fused fp32 -> bf16 cast of x (XN), Wv (WN), Wo (WN) in one launch.
// ---------------------------------------------------------------------------
constexpr int XN = Bn * Sn * En;   // 4194304
constexpr int WN = En * En;        // 1048576

__global__ __launch_bounds__(256)
void cast3(const float* __restrict__ x, const float* __restrict__ Wv,
           const float* __restrict__ Wo, unsigned short* __restrict__ xb,
           unsigned short* __restrict__ Wvb, unsigned short* __restrict__ Wob)
{
    const int i = (blockIdx.x * 256 + threadIdx.x) * 4;
    const float* src; unsigned short* dst; int off;
    if (i < XN)           { src = x;  dst = xb;  off = i; }
    else if (i < XN + WN) { src = Wv; dst = Wvb; off = i - XN; }
    else                  { src = Wo; dst = Wob; off = i - XN - WN; }
    const float4 v = *(const float4*)(src + off);
    ushort4 o;
    o.x = f2bf(v.x); o.y = f2bf(v.y); o.z = f2bf(v.z); o.w = f2bf(v.w);
    *(ushort4*)(dst + off) = o;
}

// ---------------------------------------------------------------------------
// bf16 MFMA GEMM (NT) with register-prefetch pipeline — R7: spill-free.
// C[m,n] = sum_k A[m,k]*W[n,k] + bias[n].
// Tile 128(M) x 64(N), BK=64, 256 threads = 4 waves in 2x2, wave tile 64x32.
// Staging: global -> named uint4 VGPRs -> ds_write_b128. Loads for iter i+1
// issue before iter i's compute; targeting private VGPRs they are not
// drained at __syncthreads and stay in flight across the MFMAs (vmcnt wait
// lands on the NEXT iteration's ds_write, a register dependency).
// R6's version put the staging buffers in scratch (arrays through lambdas,
// WRITE_SIZE 193 MB); here they are 12 individually named uint4 locals.
// LDS layout: 1024 B chunk = 16 rows x 32 k in fragment order, lane l ->
// slot l*16 B (conflict-free b128 writes and reads).
// ---------------------------------------------------------------------------
#define LOAD6(k0, r0, r1, r2, r3, r4, r5)            \
    r0 = *(const uint4*)(gA0 + (k0));                \
    r1 = *(const uint4*)(gA0 + (k0) + 32);           \
    r2 = *(const uint4*)(gA1 + (k0));                \
    r3 = *(const uint4*)(gA1 + (k0) + 32);           \
    r4 = *(const uint4*)(gB0 + (k0));                \
    r5 = *(const uint4*)(gB0 + (k0) + 32);

#define STORE6(r0, r1, r2, r3, r4, r5)               \
    *lA00 = r0; *lA01 = r1;                          \
    *lA10 = r2; *lA11 = r3;                          \
    *lB00 = r4; *lB01 = r5;

#define COMPUTE()                                                                              \
    {                                                                                          \
        bf16x8 af[4][2], bfr[2][2];                                                            \
        _Pragma("unroll")                                                                      \
        for (int i = 0; i < 4; ++i)                                                            \
            _Pragma("unroll")                                                                  \
            for (int kh = 0; kh < 2; ++kh)                                                     \
                af[i][kh] = *(const bf16x8*)&As[((wr * 4 + i) * 2 + kh) * 512 + lane * 8];      \
        _Pragma("unroll")                                                                      \
        for (int j = 0; j < 2; ++j)                                                            \
            _Pragma("unroll")                                                                  \
            for (int kh = 0; kh < 2; ++kh)                                                     \
                bfr[j][kh] = *(const bf16x8*)&Bs[((wc * 2 + j) * 2 + kh) * 512 + lane * 8];     \
        _Pragma("unroll")                                                                      \
        for (int kh = 0; kh < 2; ++kh)                                                         \
            _Pragma("unroll")                                                                  \
            for (int i = 0; i < 4; ++i)                                                        \
                _Pragma("unroll")                                                              \
                for (int j = 0; j < 2; ++j)                                                    \
                    acc[i][j] = __builtin_amdgcn_mfma_f32_16x16x32_bf16(af[i][kh], bfr[j][kh], \
                                                                        acc[i][j], 0, 0, 0);   \
    }

template<bool APPLY_MASK, bool OUT_BF16, bool FUSE_CSUM>
__global__ __launch_bounds__(256)
void gemm_pipe(const unsigned short* __restrict__ A, const unsigned short* __restrict__ Bw,
               const float* __restrict__ bias, const int* __restrict__ mask,
               void* __restrict__ Cv, float* __restrict__ csum, int M, int N, int K)
{
    __shared__ __align__(16) unsigned short As[128 * 64];  // 16 KB
    __shared__ __align__(16) unsigned short Bs[64 * 64];   // 8 KB

    const int tid  = threadIdx.x;
    const int lane = tid & 63;
    const int wv   = tid >> 6;      // wave 0..3
    const int wr   = wv >> 1;       // wave row (0..1) -> M
    const int wc   = wv & 1;        // wave col (0..1) -> N
    const int bm   = blockIdx.y * 128;
    const int bn   = blockIdx.x * 64;
    const int m16  = lane & 15;
    const int kq   = lane >> 4;     // k-quarter (staging) / row-quad (C/D)

    f32x4 acc[4][2] = {};

    const int rg0 = 2 * wv, rg1 = 2 * wv + 1;
    const unsigned short* gA0 = A  + (size_t)(bm + 16 * rg0 + m16) * K + kq * 8;
    const unsigned short* gA1 = A  + (size_t)(bm + 16 * rg1 + m16) * K + kq * 8;
    const unsigned short* gB0 = Bw + (size_t)(bn + 16 * wv  + m16) * K + kq * 8;
    uint4* lA00 = (uint4*)&As[(rg0 * 2 + 0) * 512 + lane * 8];
    uint4* lA01 = (uint4*)&As[(rg0 * 2 + 1) * 512 + lane * 8];
    uint4* lA10 = (uint4*)&As[(rg1 * 2 + 0) * 512 + lane * 8];
    uint4* lA11 = (uint4*)&As[(rg1 * 2 + 1) * 512 + lane * 8];
    uint4* lB00 = (uint4*)&Bs[(wv  * 2 + 0) * 512 + lane * 8];
    uint4* lB01 = (uint4*)&Bs[(wv  * 2 + 1) * 512 + lane * 8];

    // 12 individually named staging registers — two 6-reg sets.
    uint4 p0, p1, p2, p3, p4, p5;
    uint4 q0, q1, q2, q3, q4, q5;

    LOAD6(0, p0, p1, p2, p3, p4, p5);
    // K=1024, BK=64 -> 16 iterations, 2x unrolled (alternating reg sets).
#pragma unroll 1
    for (int it = 0; it < 8; ++it) {
        const int kbase = it * 128;
        __syncthreads();                        // prev compute's LDS reads done
        STORE6(p0, p1, p2, p3, p4, p5);         // waits vmcnt for p (1 iter old)
        __syncthreads();                        // writes visible
        LOAD6(kbase + 64, q0, q1, q2, q3, q4, q5);   // in flight across MFMAs
        COMPUTE();

        __syncthreads();
        STORE6(q0, q1, q2, q3, q4, q5);
        __syncthreads();
        if (it < 7) { LOAD6(kbase + 128, p0, p1, p2, p3, p4, p5); }
        COMPUTE();
    }

    // Epilogue. C/D layout: col = lane&15, row = (lane>>4)*4 + reg.
    float colsum[2] = {0.0f, 0.0f};
#pragma unroll
    for (int i = 0; i < 4; ++i) {
        const int r0 = bm + wr * 64 + i * 16 + kq * 4;
#pragma unroll
        for (int j = 0; j < 2; ++j) {
            const int c0 = bn + wc * 32 + j * 16 + m16;
            const float bcol = bias[c0];
#pragma unroll
            for (int r = 0; r < 4; ++r) {
                const int row = r0 + r;
                float val = acc[i][j][r] + bcol;
                if (APPLY_MASK) val = (mask[row] == 0) ? 0.0f : val;
                if (FUSE_CSUM) colsum[j] += val;
                if (OUT_BF16)
                    ((unsigned short*)Cv)[(size_t)row * N + c0] = f2bf(val);
                else
                    ((float*)Cv)[(size_t)row * N + c0] = val;
            }
        }
    }

    if (FUSE_CSUM) {
        // Wave wr's 64 rows are exactly global chunk gc = 2*blockIdx.y + wr.
        const int gc = 2 * blockIdx.y + wr;
#pragma unroll
        for (int j = 0; j < 2; ++j) {
            float s = colsum[j];
            s += __shfl_xor(s, 16, 64);
            s += __shfl_xor(s, 32, 64);
            if (kq == 0)
                csum[(size_t)gc * En + bn + wc * 32 + j * 16 + m16] = s;
        }
    }
}

// ---------------------------------------------------------------------------
// combine: inline exclusive scan of csum (32 chunk sums per column) +
// within-chunk prefix + weighted combine -> opre (bf16).
// out_pre[b,i,e] = (w2*Pref[i&~1] + (i odd)*w1*vm[i-1] + w0*(T - Pref[i])) / Z
// Z = (i&~1)*w2 + (i odd)*w1 + (S-i)*w0 + 1e-8   (pre-mask normalization)
// 2 columns/thread (same head since e is even and dh=64).
// ---------------------------------------------------------------------------
__global__ __launch_bounds__(256)
void combine(const unsigned short* __restrict__ vm, const float* __restrict__ csum,
             const float* __restrict__ hier, unsigned short* __restrict__ opre)
{
    const int ep = blockIdx.x * 256 + threadIdx.x;
    const int e = ep * 2;
    const int c = blockIdx.y;
    const int b = blockIdx.z;
    const int h = e >> 6;   // dh = 64

    const float w0 = hier[((size_t)b * Hn + h) * 3 + 0];
    const float w1 = hier[((size_t)b * Hn + h) * 3 + 1] * 0.5f;
    const float w2 = hier[((size_t)b * Hn + h) * 3 + 2] * 0.25f;

    // Inline exclusive scan over this batch's 32 chunk sums (L2-hot, 256 KB).
    float run0 = 0.0f, run1 = 0.0f, T0 = 0.0f, T1 = 0.0f;
    const int g0 = b * NCH;
    for (int c2 = 0; c2 < NCH; ++c2) {
        const size_t off = (size_t)(g0 + c2) * En + e;
        const float v0 = csum[off], v1 = csum[off + 1];
        if (c2 < c) { run0 += v0; run1 += v1; }
        T0 += v0; T1 += v1;
    }

    float prev0 = 0.0f, prev1 = 0.0f;
    const size_t base = ((size_t)b * Sn + c * CHUNK) * En + e;

    for (int t = 0; t < CHUNK; ++t) {
        const int i = c * CHUNK + t;
        const uint32_t u = *(const uint32_t*)(vm + base + (size_t)t * En);
        const float cur0 = bf2f_lo(u), cur1 = bf2f_hi(u);
        float num0, num1, Z;
        if (i & 1) {
            num0 = w2 * (run0 - prev0) + w1 * prev0 + w0 * (T0 - run0);
            num1 = w2 * (run1 - prev1) + w1 * prev1 + w0 * (T1 - run1);
            Z = (float)(i - 1) * w2 + w1 + (float)(Sn - i) * w0 + 1e-8f;
        } else {
            num0 = w2 * run0 + w0 * (T0 - run0);
            num1 = w2 * run1 + w0 * (T1 - run1);
            Z = (float)i * w2 + (float)(Sn - i) * w0 + 1e-8f;
        }
        const float rz = 1.0f / Z;
        const uint32_t o = (uint32_t)f2bf(num0 * rz) | ((uint32_t)f2bf(num1 * rz) << 16);
        *(uint32_t*)(opre + base + (size_t)t * En) = o;
        run0 += cur0; run1 += cur1;
        prev0 = cur0; prev1 = cur1;
    }
}

// ---------------------------------------------------------------------------
extern "C" void kernel_launch(void* const* d_in, const int* in_sizes, int n_in,
                              void* d_out, int out_size, void* d_ws, size_t ws_size,
                              hipStream_t stream)
{
    // 0:x 1:attention_mask 2:level_indices 3:Wq 4:bq 5:Wk 6:bk 7:Wv 8:bv 9:hier 10:Wo 11:bo
    const float* x    = (const float*)d_in[0];
    const int*   mask = (const int*)d_in[1];
    const float* Wv   = (const float*)d_in[7];
    const float* bv   = (const float*)d_in[8];
    const float* hier = (const float*)d_in[9];
    const float* Wo   = (const float*)d_in[10];
    const float* bo   = (const float*)d_in[11];
    float* out = (float*)d_out;

    const int M = Mtot, N = En, K = En;

    char* ws = (char*)d_ws;
    unsigned short* xb    = (unsigned short*)ws;  ws += (size_t)M * K * 2;        // 8 MB
    unsigned short* Wvb   = (unsigned short*)ws;  ws += (size_t)N * K * 2;        // 2 MB
    unsigned short* Wob   = (unsigned short*)ws;  ws += (size_t)N * K * 2;        // 2 MB
    unsigned short* vmb   = (unsigned short*)ws;  ws += (size_t)M * N * 2;        // 8 MB
    float*          csum  = (float*)ws;           ws += (size_t)GCH * En * 4;     // 256 KB
    unsigned short* opreb = (unsigned short*)ws;  ws += (size_t)M * N * 2;        // 8 MB

    dim3 threads(256);

    // Fused casts to bf16 (x, Wv, Wo)
    cast3<<<dim3((XN + 2 * WN) / 1024), threads, 0, stream>>>(x, Wv, Wo, xb, Wvb, Wob);

    dim3 gemm_grid(N / 64, M / 128);   // (16, 32) = 512 blocks = 2/CU

    // 1) vm = mask ? (x @ Wv.T + bv) : 0 (bf16) + fused per-chunk column sums
    gemm_pipe<true, true, true><<<gemm_grid, threads, 0, stream>>>(xb, Wvb, bv, mask, vmb, csum, M, N, K);
    // 2) weighted combine (inline csum scan) -> opre (bf16)
    combine<<<dim3(En / 512, NCH, Bn), threads, 0, stream>>>(vmb, csum, hier, opreb);
    // 3) out = opre @ Wo.T + bo (fp32 out)
    gemm_pipe<false, false, false><<<gemm_grid, threads, 0, stream>>>(opreb, Wob, bo, nullptr, out, nullptr, M, N, K);
}

// Round 8
// 169.082 us; speedup vs baseline: 1.5141x; 1.0075x over previous
//
#include <hip/hip_runtime.h>
#include <cstdint>
#include <cstddef>

// Problem constants (B, S, E, H, MAXLEN) = (2, 2048, 1024, 16, 2048)
constexpr int Sn = 2048;
constexpr int En = 1024;
constexpr int Bn = 2;
constexpr int Hn = 16;
constexpr int NCH = 32;            // chunks per batch (S/CHUNK)
constexpr int CHUNK = 64;
constexpr int Mtot = Bn * Sn;      // 4096
constexpr int GCH = Mtot / CHUNK;  // 64 global chunks

typedef __bf16 bf16x8 __attribute__((ext_vector_type(8)));
typedef float  f32x4  __attribute__((ext_vector_type(4)));

__device__ __forceinline__ unsigned short f2bf(float f) {
    union { float f; uint32_t u; } v; v.f = f;
    const uint32_t u = v.u;
    return (unsigned short)((u + 0x7fffu + ((u >> 16) & 1u)) >> 16);  // RNE
}
__device__ __forceinline__ float bf2f(unsigned short s) {
    union { uint32_t u; float f; } v; v.u = (uint32_t)s << 16; return v.f;
}

// ---------------------------------------------------------------------------
// Fused fp32 -> bf16 cast of x (XN), Wv (WN), Wo (WN) in one launch.
// ---------------------------------------------------------------------------
constexpr int XN = Bn * Sn * En;   // 4194304
constexpr int WN = En * En;        // 1048576

__global__ __launch_bounds__(256)
void cast3(const float* __restrict__ x, const float* __restrict__ Wv,
           const float* __restrict__ Wo, unsigned short* __restrict__ xb,
           unsigned short* __restrict__ Wvb, unsigned short* __restrict__ Wob)
{
    const int i = (blockIdx.x * 256 + threadIdx.x) * 4;
    const float* src; unsigned short* dst; int off;
    if (i < XN)           { src = x;  dst = xb;  off = i; }
    else if (i < XN + WN) { src = Wv; dst = Wvb; off = i - XN; }
    else                  { src = Wo; dst = Wob; off = i - XN - WN; }
    const float4 v = *(const float4*)(src + off);
    ushort4 o;
    o.x = f2bf(v.x); o.y = f2bf(v.y); o.z = f2bf(v.z); o.w = f2bf(v.w);
    *(ushort4*)(dst + off) = o;
}

// ---------------------------------------------------------------------------
// bf16 MFMA GEMM (NT), register-prefetch pipeline + XCD-aware swizzle (R8).
// C[m,n] = sum_k A[m,k]*W[n,k] + bias[n].
// Tile 128(M) x 64(N), BK=64, 256 threads = 4 waves in 2x2, wave tile 64x32.
// Swizzle: id = by*16+bx -> xcd = id&7, slot = id>>3, by = xcd*4 + slot/16,
// bx = slot%16. Each XCD owns 4 contiguous row-blocks x all col-blocks:
// working set A 1 MB + B 2 MB < 4 MB per-XCD L2, so the 16x A re-reads hit
// L2 (~200 cyc) instead of L3/HBM (~900) — shortens the vmcnt tails that
// stall the staging barriers.
// Staging: global -> 12 named uint4 VGPRs -> ds_write_b128 (loads for iter
// i+1 issue before iter i's compute; private VGPRs are not drained at
// __syncthreads, so they stay in flight across the MFMAs).
// LDS layout: 1024 B chunk = 16 rows x 32 k in fragment order, lane l ->
// slot l*16 B (conflict-free b128 writes and reads).
// ---------------------------------------------------------------------------
#define LOAD6(k0, r0, r1, r2, r3, r4, r5)            \
    r0 = *(const uint4*)(gA0 + (k0));                \
    r1 = *(const uint4*)(gA0 + (k0) + 32);           \
    r2 = *(const uint4*)(gA1 + (k0));                \
    r3 = *(const uint4*)(gA1 + (k0) + 32);           \
    r4 = *(const uint4*)(gB0 + (k0));                \
    r5 = *(const uint4*)(gB0 + (k0) + 32);

#define STORE6(r0, r1, r2, r3, r4, r5)               \
    *lA00 = r0; *lA01 = r1;                          \
    *lA10 = r2; *lA11 = r3;                          \
    *lB00 = r4; *lB01 = r5;

#define COMPUTE()                                                                              \
    {                                                                                          \
        bf16x8 af[4][2], bfr[2][2];                                                            \
        _Pragma("unroll")                                                                      \
        for (int i = 0; i < 4; ++i)                                                            \
            _Pragma("unroll")                                                                  \
            for (int kh = 0; kh < 2; ++kh)                                                     \
                af[i][kh] = *(const bf16x8*)&As[((wr * 4 + i) * 2 + kh) * 512 + lane * 8];      \
        _Pragma("unroll")                                                                      \
        for (int j = 0; j < 2; ++j)                                                            \
            _Pragma("unroll")                                                                  \
            for (int kh = 0; kh < 2; ++kh)                                                     \
                bfr[j][kh] = *(const bf16x8*)&Bs[((wc * 2 + j) * 2 + kh) * 512 + lane * 8];     \
        _Pragma("unroll")                                                                      \
        for (int kh = 0; kh < 2; ++kh)                                                         \
            _Pragma("unroll")                                                                  \
            for (int i = 0; i < 4; ++i)                                                        \
                _Pragma("unroll")                                                              \
                for (int j = 0; j < 2; ++j)                                                    \
                    acc[i][j] = __builtin_amdgcn_mfma_f32_16x16x32_bf16(af[i][kh], bfr[j][kh], \
                                                                        acc[i][j], 0, 0, 0);   \
    }

template<bool APPLY_MASK, bool OUT_BF16, bool FUSE_CSUM>
__global__ __launch_bounds__(256)
void gemm_pipe(const unsigned short* __restrict__ A, const unsigned short* __restrict__ Bw,
               const float* __restrict__ bias, const int* __restrict__ mask,
               void* __restrict__ Cv, float* __restrict__ csum, int M, int N, int K)
{
    __shared__ __align__(16) unsigned short As[128 * 64];  // 16 KB
    __shared__ __align__(16) unsigned short Bs[64 * 64];   // 8 KB

    const int tid  = threadIdx.x;
    const int lane = tid & 63;
    const int wv   = tid >> 6;      // wave 0..3
    const int wr   = wv >> 1;       // wave row (0..1) -> M
    const int wc   = wv & 1;        // wave col (0..1) -> N
    // XCD-aware swizzle (grid is (16, 32); linear id -> xcd-contiguous rows).
    const int id   = blockIdx.y * 16 + blockIdx.x;
    const int xcd  = id & 7;
    const int slot = id >> 3;
    const int by   = xcd * 4 + (slot >> 4);
    const int bx   = slot & 15;
    const int bm   = by * 128;
    const int bn   = bx * 64;
    const int m16  = lane & 15;
    const int kq   = lane >> 4;     // k-quarter (staging) / row-quad (C/D)

    f32x4 acc[4][2] = {};

    const int rg0 = 2 * wv, rg1 = 2 * wv + 1;
    const unsigned short* gA0 = A  + (size_t)(bm + 16 * rg0 + m16) * K + kq * 8;
    const unsigned short* gA1 = A  + (size_t)(bm + 16 * rg1 + m16) * K + kq * 8;
    const unsigned short* gB0 = Bw + (size_t)(bn + 16 * wv  + m16) * K + kq * 8;
    uint4* lA00 = (uint4*)&As[(rg0 * 2 + 0) * 512 + lane * 8];
    uint4* lA01 = (uint4*)&As[(rg0 * 2 + 1) * 512 + lane * 8];
    uint4* lA10 = (uint4*)&As[(rg1 * 2 + 0) * 512 + lane * 8];
    uint4* lA11 = (uint4*)&As[(rg1 * 2 + 1) * 512 + lane * 8];
    uint4* lB00 = (uint4*)&Bs[(wv  * 2 + 0) * 512 + lane * 8];
    uint4* lB01 = (uint4*)&Bs[(wv  * 2 + 1) * 512 + lane * 8];

    // 12 individually named staging registers — two 6-reg sets (no arrays:
    // arrays through lambdas went to scratch in R6, WRITE_SIZE 193 MB).
    uint4 p0, p1, p2, p3, p4, p5;
    uint4 q0, q1, q2, q3, q4, q5;

    LOAD6(0, p0, p1, p2, p3, p4, p5);
    // K=1024, BK=64 -> 16 iterations, 2x unrolled (alternating reg sets).
#pragma unroll 1
    for (int it = 0; it < 8; ++it) {
        const int kbase = it * 128;
        __syncthreads();                        // prev compute's LDS reads done
        STORE6(p0, p1, p2, p3, p4, p5);         // waits vmcnt for p (1 iter old)
        __syncthreads();                        // writes visible
        LOAD6(kbase + 64, q0, q1, q2, q3, q4, q5);   // in flight across MFMAs
        COMPUTE();

        __syncthreads();
        STORE6(q0, q1, q2, q3, q4, q5);
        __syncthreads();
        if (it < 7) { LOAD6(kbase + 128, p0, p1, p2, p3, p4, p5); }
        COMPUTE();
    }

    // Epilogue. C/D layout: col = lane&15, row = (lane>>4)*4 + reg.
    float colsum[2] = {0.0f, 0.0f};
#pragma unroll
    for (int i = 0; i < 4; ++i) {
        const int r0 = bm + wr * 64 + i * 16 + kq * 4;
#pragma unroll
        for (int j = 0; j < 2; ++j) {
            const int c0 = bn + wc * 32 + j * 16 + m16;
            const float bcol = bias[c0];
#pragma unroll
            for (int r = 0; r < 4; ++r) {
                const int row = r0 + r;
                float val = acc[i][j][r] + bcol;
                if (APPLY_MASK) val = (mask[row] == 0) ? 0.0f : val;
                if (FUSE_CSUM) colsum[j] += val;
                if (OUT_BF16)
                    ((unsigned short*)Cv)[(size_t)row * N + c0] = f2bf(val);
                else
                    ((float*)Cv)[(size_t)row * N + c0] = val;
            }
        }
    }

    if (FUSE_CSUM) {
        // Wave wr's 64 rows are exactly global chunk gc = 2*by + wr.
        const int gc = 2 * by + wr;
#pragma unroll
        for (int j = 0; j < 2; ++j) {
            float s = colsum[j];
            s += __shfl_xor(s, 16, 64);
            s += __shfl_xor(s, 32, 64);
            if (kq == 0)
                csum[(size_t)gc * En + bn + wc * 32 + j * 16 + m16] = s;
        }
    }
}

// ---------------------------------------------------------------------------
// combine: inline exclusive scan of csum (32 chunk sums per column) +
// within-chunk prefix + weighted combine -> opre (bf16).
// out_pre[b,i,e] = (w2*Pref[i&~1] + (i odd)*w1*vm[i-1] + w0*(T - Pref[i])) / Z
// Z = (i&~1)*w2 + (i odd)*w1 + (S-i)*w0 + 1e-8   (pre-mask normalization)
// R8: 1 column/thread (grid x = En/256 = 4) -> 2x thread parallelism to hide
// the strided serial-loop latency (this kernel is occupancy-bound, not BW).
// ---------------------------------------------------------------------------
__global__ __launch_bounds__(256)
void combine(const unsigned short* __restrict__ vm, const float* __restrict__ csum,
             const float* __restrict__ hier, unsigned short* __restrict__ opre)
{
    const int e = blockIdx.x * 256 + threadIdx.x;
    const int c = blockIdx.y;
    const int b = blockIdx.z;
    const int h = e >> 6;   // dh = 64

    const float w0 = hier[((size_t)b * Hn + h) * 3 + 0];
    const float w1 = hier[((size_t)b * Hn + h) * 3 + 1] * 0.5f;
    const float w2 = hier[((size_t)b * Hn + h) * 3 + 2] * 0.25f;

    // Inline exclusive scan over this batch's 32 chunk sums (L2-hot, 256 KB).
    float run = 0.0f, T = 0.0f;
    const int g0 = b * NCH;
    for (int c2 = 0; c2 < NCH; ++c2) {
        const float v = csum[(size_t)(g0 + c2) * En + e];
        if (c2 < c) run += v;
        T += v;
    }

    float prev = 0.0f;
    const size_t base = ((size_t)b * Sn + c * CHUNK) * En + e;

    for (int t = 0; t < CHUNK; ++t) {
        const int i = c * CHUNK + t;
        const float cur = bf2f(vm[base + (size_t)t * En]);
        float num, Z;
        if (i & 1) {
            num = w2 * (run - prev) + w1 * prev + w0 * (T - run);
            Z = (float)(i - 1) * w2 + w1 + (float)(Sn - i) * w0 + 1e-8f;
        } else {
            num = w2 * run + w0 * (T - run);
            Z = (float)i * w2 + (float)(Sn - i) * w0 + 1e-8f;
        }
        opre[base + (size_t)t * En] = f2bf(num / Z);
        run += cur;
        prev = cur;
    }
}

// ---------------------------------------------------------------------------
extern "C" void kernel_launch(void* const* d_in, const int* in_sizes, int n_in,
                              void* d_out, int out_size, void* d_ws, size_t ws_size,
                              hipStream_t stream)
{
    // 0:x 1:attention_mask 2:level_indices 3:Wq 4:bq 5:Wk 6:bk 7:Wv 8:bv 9:hier 10:Wo 11:bo
    const float* x    = (const float*)d_in[0];
    const int*   mask = (const int*)d_in[1];
    const float* Wv   = (const float*)d_in[7];
    const float* bv   = (const float*)d_in[8];
    const float* hier = (const float*)d_in[9];
    const float* Wo   = (const float*)d_in[10];
    const float* bo   = (const float*)d_in[11];
    float* out = (float*)d_out;

    const int M = Mtot, N = En, K = En;

    char* ws = (char*)d_ws;
    unsigned short* xb    = (unsigned short*)ws;  ws += (size_t)M * K * 2;        // 8 MB
    unsigned short* Wvb   = (unsigned short*)ws;  ws += (size_t)N * K * 2;        // 2 MB
    unsigned short* Wob   = (unsigned short*)ws;  ws += (size_t)N * K * 2;        // 2 MB
    unsigned short* vmb   = (unsigned short*)ws;  ws += (size_t)M * N * 2;        // 8 MB
    float*          csum  = (float*)ws;           ws += (size_t)GCH * En * 4;     // 256 KB
    unsigned short* opreb = (unsigned short*)ws;  ws += (size_t)M * N * 2;        // 8 MB

    dim3 threads(256);

    // Fused casts to bf16 (x, Wv, Wo)
    cast3<<<dim3((XN + 2 * WN) / 1024), threads, 0, stream>>>(x, Wv, Wo, xb, Wvb, Wob);

    dim3 gemm_grid(16, 32);   // 512 blocks = 2/CU (swizzled inside the kernel)

    // 1) vm = mask ? (x @ Wv.T + bv) : 0 (bf16) + fused per-chunk column sums
    gemm_pipe<true, true, true><<<gemm_grid, threads, 0, stream>>>(xb, Wvb, bv, mask, vmb, csum, M, N, K);
    // 2) weighted combine (inline csum scan) -> opre (bf16)
    combine<<<dim3(En / 256, NCH, Bn), threads, 0, stream>>>(vmb, csum, hier, opreb);
    // 3) out = opre @ Wo.T + bo (fp32 out)
    gemm_pipe<false, false, false><<<gemm_grid, threads, 0, stream>>>(opreb, Wob, bo, nullptr, out, nullptr, M, N, K);
}